// Round 8
// baseline (332.212 us; speedup 1.0000x reference)
//
#include <hip/hip_runtime.h>
#include <math.h>

// SRP-PHAT via Chebyshev factorization (degree 32; tail ~1e-7 at z_max=14.67).
// G[bt, p*32+c] = sum_f Xnorm_{re|im}[bt,f,p] * coef_c(w_f*S), then
// Ys[bt,d] = sum_k G[bt,k] * Tt[k,d]. Diagonal mic pairs dropped.
// Round 14: stageA = DIRECT REGISTER GATHER, no LDS staging at all. Three
// structural staging variants (lockstep barrier, DMA 1-barrier, barrier-free
// independent waves) all pinned at 84-90us vs ~22us pipe models -- the
// invariant was the global->LDS->ds_read round trip + vmcnt(0) drain each
// ~440-cyc chunk at 2.9 waves/SIMD. In the (p,half) lane layout each lane
// OWNS its pair's (xr,xi): no cross-lane sharing -> staging buys nothing.
// Now: lane loads 2 dwords per (bt,f) straight to VGPRs (one wave-inst = one
// 288B row, ~78% utilized), manual 1-deep A/B prefetch (16 floats, not the
// 48-reg float4 state that spilled in r7/r9), compiler-counted waitcnt.
// LDS = sCall only (5.6KB). gemmB 256x64/16x4, LDS-transpose reduceG,
// fused k_init unchanged from the passing r13 kernel.

#define F_BINS  513
#define M_TOTAL 1000
#define D_TOTAL 2562
#define D_PAD   2688          // 42 * 64
#define NPAIR   28
#define NC      32
#define K2      (NPAIR * NC)  // 896
#define S_SCALE 4.67f         // |dtau| <= 4.665
#define NBT     4             // bt per WAVE
#define WPB     2             // waves per block
#define FSPLIT  12            // stageA f-splits
#define KSPB    4             // gemmB K-splits
#define KPS     224           // K2 / KSPB
#define BT_PAD  1024          // Gt row length (bt padded)
#define DBLK    11            // ceil(D_PAD/256) for k_init ttab part

// ws layout (float offsets); total 14,094,464 floats = 56.4 MB
#define OFF_COEF 0
#define OFF_TT   16512
#define OFF_GT   (OFF_TT + (size_t)K2 * D_PAD)            // 2,424,960
#define OFF_GP   (OFF_GT + (size_t)K2 * BT_PAD)           // 3,342,464
#define OFF_YS   OFF_GP   // Ysp (4 planes = 10,752,000) aliases Gp (12 planes, same)

__device__ __constant__ int c_ptab[NPAIR] = {1,2,3,4,5,6,7, 9,10,11,12,13,14,
                                             16,17,18,19,20, 22,23,24,25,
                                             27,28,29, 31,32, 34};
__device__ __constant__ int c_i0[NPAIR] = {0,0,0,0,0,0,0, 1,1,1,1,1,1,
                                           2,2,2,2,2, 3,3,3,3, 4,4,4, 5,5, 6};
__device__ __constant__ int c_i1[NPAIR] = {1,2,3,4,5,6,7, 2,3,4,5,6,7,
                                           3,4,5,6,7, 4,5,6,7, 5,6,7, 6,7, 7};

// ---- fused init: blocks [0, DBLK*NPAIR) build Tt; blocks [.., +513) build
// coefEO[f][32] (c<16 -> cos-coeff a_{2c}(z_f); c>=16 -> sin b_{2c'+1}).
__global__ void k_init(const float* __restrict__ taus,
                       float* __restrict__ coefEO, float* __restrict__ Tt) {
    __shared__ double sHC[NC][NC + 1];
    __shared__ double sHS[NC][NC + 1];
    if (blockIdx.x < DBLK * NPAIR) {
        // ---- Tt[p*32+c][d]: c<16 -> T_{2c}(u), c>=16 -> T_{2(c-16)+1}(u) ---
        const int p = blockIdx.x / DBLK;
        const int d = (blockIdx.x % DBLK) * 256 + threadIdx.x;
        if (d >= D_PAD) return;
        const bool live = d < D_TOTAL;
        const int dd = live ? d : 0;
        const float u = (taus[dd * 8 + c_i0[p]] - taus[dd * 8 + c_i1[p]]) * (1.0f / S_SCALE);
        float* base = Tt + (size_t)p * 32 * D_PAD + d;
        base[0] = live ? 1.f : 0.f;                       // n=0 -> c=0
        base[(size_t)16 * D_PAD] = live ? u : 0.f;        // n=1 -> c=16
        float tp = 1.f, tc = u;
        const float u2 = 2.f * u;
        for (int n = 2; n < NC; ++n) {
            float tn = u2 * tc - tp;
            tp = tc; tc = tn;
            int c = (n & 1) ? 16 + (n >> 1) : (n >> 1);
            base[(size_t)c * D_PAD] = live ? tn : 0.f;
        }
    } else {
        const int f = blockIdx.x - DBLK * NPAIR;
        const int t = threadIdx.x;
        if (t < 32) {
            const double z = (double)f * (M_PI / 512.0) * (double)S_SCALE;
            double th = M_PI * (t + 0.5) / NC;
            double ct = cos(th);
            double hs, hc;
            sincos(z * ct, &hs, &hc);
            double cp = 1.0, cc = ct, c2 = 2.0 * ct;
            sHC[0][t] = hc;      sHS[0][t] = hs;
            sHC[1][t] = hc * cc; sHS[1][t] = hs * cc;
            for (int n = 2; n < NC; ++n) {
                double cn = c2 * cc - cp;
                cp = cc; cc = cn;
                sHC[n][t] = hc * cn;
                sHS[n][t] = hs * cn;
            }
        }
        __syncthreads();
        if (t < 32) {
            const int n = (t < 16) ? 2 * t : 2 * (t - 16) + 1;
            double sum = 0.0;
            if (t < 16) { for (int j = 0; j < NC; ++j) sum += sHC[n][j]; }
            else        { for (int j = 0; j < NC; ++j) sum += sHS[n][j]; }
            double scale = (n == 0) ? (1.0 / NC) : (2.0 / NC);
            coefEO[f * 32 + t] = (float)(sum * scale);
        }
    }
}

// ---- stage A: Gp[split][bt][p*32+c] ----------------------------------------
// 2 independent waves per block, each owns NBT=4 bt rows. Lane = pair p
// (l&31) x coef-half (l>>5); each lane computes re (8 even coefs) + im
// (8 odd coefs) -> 64 acc. (xr,xi) gathered DIRECTLY global->register:
// per (bt,f) two dword loads at row+qq / row+qq+36 (one wave-inst covers one
// 288B row; halves read identical addrs -> dedup in the coalescer). Manual
// A/B 1-f-deep prefetch keeps next-f loads in flight under current-f FMAs;
// compiler emits counted s_waitcnt. LDS = sCall coef table only. No main-loop
// barriers, no DMA, no inline asm.
__global__ __launch_bounds__(128, 3) void k_stageA(
    const float* __restrict__ XXs, const float* __restrict__ coefEO,
    float* __restrict__ Gp)
{
    __shared__ float sCall[44][32];   // whole split's coef table
    const int t     = threadIdx.x;
    const int wave  = t >> 6;
    const int lane  = t & 63;
    const int split = blockIdx.y;
    const int fbeg  = (F_BINS * split) / FSPLIT;
    const int fend  = (F_BINS * (split + 1)) / FSPLIT;
    const int nf    = fend - fbeg;            // 42 or 43
    const int btg0  = (blockIdx.x * WPB + wave) * NBT;
    const int p     = lane & 31;
    const int half  = lane >> 5;
    const int qq    = c_ptab[p < NPAIR ? p : NPAIR - 1];

    // whole-split coef table (cooperative, both waves); rows >= nf unused
    for (int e = t; e < 44 * 8; e += 128) {
        int fl = e >> 3, q = e & 7;
        float4 v = {0.f, 0.f, 0.f, 0.f};
        if (fl < nf) v = *(const float4*)&coefEO[(fbeg + fl) * 32 + q * 4];
        *(float4*)&sCall[fl][q * 4] = v;
    }

    // per-bt row base pointers (lane-specific qq folded in)
    const float* rp[NBT];
    #pragma unroll
    for (int bt = 0; bt < NBT; ++bt)
        rp[bt] = XXs + ((size_t)(btg0 + bt) * F_BINS + fbeg) * 72 + qq;

    float acc[NBT][16] = {};
    float xrA[NBT], xiA[NBT], xrB[NBT], xiB[NBT];

    auto loadF = [&](int cr, float (&xr)[NBT], float (&xi)[NBT]) {
        #pragma unroll
        for (int bt = 0; bt < NBT; ++bt) {
            const float* ep = rp[bt] + (size_t)cr * 72;
            xr[bt] = ep[0];
            xi[bt] = ep[36];
        }
    };
    // 1 f x 4 bt x (re 8 + im 8) FMAs; inline normalize (1e-37 stays normal
    // under FTZ -> rsqrtf never sees +0 -> always finite)
    auto computeF = [&](int cr, float (&xr)[NBT], float (&xi)[NBT]) {
        float4 cA0 = *(const float4*)&sCall[cr][half * 8];
        float4 cA1 = *(const float4*)&sCall[cr][half * 8 + 4];
        float4 cB0 = *(const float4*)&sCall[cr][16 + half * 8];
        float4 cB1 = *(const float4*)&sCall[cr][16 + half * 8 + 4];
        #pragma unroll
        for (int bt = 0; bt < NBT; ++bt) {
            float inv = rsqrtf(xr[bt] * xr[bt] + xi[bt] * xi[bt] + 1e-37f);
            float ar = xr[bt] * inv, ai = xi[bt] * inv;
            acc[bt][0]  = fmaf(ar, cA0.x, acc[bt][0]);
            acc[bt][1]  = fmaf(ar, cA0.y, acc[bt][1]);
            acc[bt][2]  = fmaf(ar, cA0.z, acc[bt][2]);
            acc[bt][3]  = fmaf(ar, cA0.w, acc[bt][3]);
            acc[bt][4]  = fmaf(ar, cA1.x, acc[bt][4]);
            acc[bt][5]  = fmaf(ar, cA1.y, acc[bt][5]);
            acc[bt][6]  = fmaf(ar, cA1.z, acc[bt][6]);
            acc[bt][7]  = fmaf(ar, cA1.w, acc[bt][7]);
            acc[bt][8]  = fmaf(ai, cB0.x, acc[bt][8]);
            acc[bt][9]  = fmaf(ai, cB0.y, acc[bt][9]);
            acc[bt][10] = fmaf(ai, cB0.z, acc[bt][10]);
            acc[bt][11] = fmaf(ai, cB0.w, acc[bt][11]);
            acc[bt][12] = fmaf(ai, cB1.x, acc[bt][12]);
            acc[bt][13] = fmaf(ai, cB1.y, acc[bt][13]);
            acc[bt][14] = fmaf(ai, cB1.z, acc[bt][14]);
            acc[bt][15] = fmaf(ai, cB1.w, acc[bt][15]);
        }
    };

    loadF(0, xrA, xiA);
    __syncthreads();   // sCall ready (only barrier in the kernel)
    int cr = 0;
    for (; cr + 2 <= nf; cr += 2) {
        loadF(cr + 1, xrB, xiB);          // in flight under compute(A)
        computeF(cr, xrA, xiA);
        if (cr + 2 < nf) loadF(cr + 2, xrA, xiA);  // in flight under compute(B)
        computeF(cr + 1, xrB, xiB);
    }
    if (cr < nf) computeF(cr, xrA, xiA);  // odd-nf tail (A loaded in last iter)

    if (p < NPAIR) {
        float* gsp = Gp + (size_t)split * M_TOTAL * K2;
        #pragma unroll
        for (int bt = 0; bt < NBT; ++bt) {
            float* g = gsp + (size_t)(btg0 + bt) * K2 + p * 32 + half * 8;
            float4 v0 = {acc[bt][0],  acc[bt][1],  acc[bt][2],  acc[bt][3]};
            float4 v1 = {acc[bt][4],  acc[bt][5],  acc[bt][6],  acc[bt][7]};
            float4 v2 = {acc[bt][8],  acc[bt][9],  acc[bt][10], acc[bt][11]};
            float4 v3 = {acc[bt][12], acc[bt][13], acc[bt][14], acc[bt][15]};
            *(float4*)&g[0]  = v0;   // c = half*8 + 0..3
            *(float4*)&g[4]  = v1;   // c = half*8 + 4..7
            *(float4*)&g[16] = v2;   // c = 16 + half*8 + 0..3
            *(float4*)&g[20] = v3;   // c = 16 + half*8 + 4..7
        }
    }
}

// ---- reduce the 12 f-split partials into transposed, padded Gt[k][bt] ------
// 32k x 64bt tile per block; LDS transpose -> both read and write coalesced.
__global__ __launch_bounds__(256) void k_reduceG(
    const float* __restrict__ Gp, float* __restrict__ Gt)
{
    __shared__ float sT[32][65];
    const int t   = threadIdx.x;
    const int k0  = blockIdx.x * 32;
    const int bt0 = blockIdx.y * 64;
    const size_t MK = (size_t)M_TOTAL * K2;
    #pragma unroll
    for (int i = 0; i < 8; ++i) {
        int e  = t + i * 256;
        int kl = e & 31, btl = e >> 5;
        int bt = bt0 + btl;
        float s = 0.f;
        if (bt < M_TOTAL) {
            const float* g = Gp + (size_t)bt * K2 + k0 + kl;
            #pragma unroll
            for (int pl = 0; pl < FSPLIT; ++pl) s += g[pl * MK];
        }
        sT[kl][btl] = s;
    }
    __syncthreads();
    #pragma unroll
    for (int i = 0; i < 8; ++i) {
        int e   = t + i * 256;
        int btl = e & 63, kl = e >> 6;
        Gt[(size_t)(k0 + kl) * BT_PAD + bt0 + btl] = sT[kl][btl];
    }
}

// ---- stage B: Ysp[split][1000][2688] partial of Gt^T @ Tt ------------------
// 256x64 tile, 16 rows x 4 cols per thread: 5 b128 (60 LDS-cyc) per 64 FMA
// (128 VALU-cyc) per kk -> VALU-bound with overlap. a-reads 2-way+broadcast,
// b-reads 2-way: both conflict-free.
#define BKB 32
__global__ __launch_bounds__(256, 4) void k_gemmB(
    const float* __restrict__ Gt, const float* __restrict__ Tt,
    float* __restrict__ Ysp)
{
    __shared__ float sA[BKB][260];   // [k][bt]
    __shared__ float sB[BKB][68];    // [k][d]
    const int t = threadIdx.x;
    const int row0 = blockIdx.x * 256;
    const int col0 = blockIdx.y * 64;
    const int koff = blockIdx.z * KPS;
    const int tx = t & 15;
    const int ty = t >> 4;
    float acc[16][4] = {};

    for (int k0 = 0; k0 < KPS; k0 += BKB) {
        __syncthreads();
        #pragma unroll
        for (int i = 0; i < 8; ++i) {   // A: 32k x 256bt, float4
            int e = t + i * 256;
            int kk = e >> 6, r4 = (e & 63) * 4;
            *(float4*)&sA[kk][r4] =
                *(const float4*)&Gt[(size_t)(koff + k0 + kk) * BT_PAD + row0 + r4];
        }
        #pragma unroll
        for (int i = 0; i < 2; ++i) {   // B: 32k x 64d, float4
            int e = t + i * 256;
            int kk = e >> 4, c4 = (e & 15) * 4;
            *(float4*)&sB[kk][c4] =
                *(const float4*)&Tt[(size_t)(koff + k0 + kk) * D_PAD + col0 + c4];
        }
        __syncthreads();
        #pragma unroll 8
        for (int kk = 0; kk < BKB; ++kk) {
            float4 b  = *(const float4*)&sB[kk][tx * 4];
            float4 a0 = *(const float4*)&sA[kk][ty * 16];
            float4 a1 = *(const float4*)&sA[kk][ty * 16 + 4];
            float4 a2 = *(const float4*)&sA[kk][ty * 16 + 8];
            float4 a3 = *(const float4*)&sA[kk][ty * 16 + 12];
            float av[16] = {a0.x, a0.y, a0.z, a0.w, a1.x, a1.y, a1.z, a1.w,
                            a2.x, a2.y, a2.z, a2.w, a3.x, a3.y, a3.z, a3.w};
            float bv[4] = {b.x, b.y, b.z, b.w};
            #pragma unroll
            for (int i = 0; i < 16; ++i)
                #pragma unroll
                for (int j = 0; j < 4; ++j)
                    acc[i][j] = fmaf(av[i], bv[j], acc[i][j]);
        }
    }
    float* yp = Ysp + (size_t)blockIdx.z * M_TOTAL * D_PAD;
    #pragma unroll
    for (int i = 0; i < 16; ++i) {
        int rg = row0 + ty * 16 + i;
        if (rg >= M_TOTAL) continue;
        float4 v = {acc[i][0], acc[i][1], acc[i][2], acc[i][3]};
        *(float4*)(yp + (size_t)rg * D_PAD + col0 + tx * 4) = v;
    }
}

// ---- argmax over summed K-split partials + doa gather ----------------------
__global__ __launch_bounds__(256) void k_argmax(
    const float* __restrict__ Ysp, const float* __restrict__ doas,
    float* __restrict__ out)
{
    __shared__ float sv[256];
    __shared__ int   si[256];
    const int row = blockIdx.x;
    const int tid = threadIdx.x;
    const float* y = Ysp + (size_t)row * D_PAD;
    const size_t PL = (size_t)M_TOTAL * D_PAD;
    float best = -INFINITY;
    int bi = D_TOTAL;
    for (int d = tid; d < D_TOTAL; d += 256) {
        float v = y[d] + y[d + PL] + y[d + 2 * PL] + y[d + 3 * PL];
        if (v > best) { best = v; bi = d; }
    }
    sv[tid] = best; si[tid] = bi;
    __syncthreads();
    for (int s = 128; s > 0; s >>= 1) {
        if (tid < s) {
            float v2 = sv[tid + s]; int i2 = si[tid + s];
            if (v2 > sv[tid] || (v2 == sv[tid] && i2 < si[tid])) { sv[tid] = v2; si[tid] = i2; }
        }
        __syncthreads();
    }
    if (tid == 0) {
        int idx = si[0];
        out[row * 3 + 0] = doas[idx * 3 + 0];
        out[row * 3 + 1] = doas[idx * 3 + 1];
        out[row * 3 + 2] = doas[idx * 3 + 2];
    }
}

extern "C" void kernel_launch(void* const* d_in, const int* in_sizes, int n_in,
                              void* d_out, int out_size, void* d_ws, size_t ws_size,
                              hipStream_t stream) {
    const float* XXs  = (const float*)d_in[0];  // (4,250,513,2,36) f32
    const float* taus = (const float*)d_in[1];  // (2562,8) f32
    const float* doas = (const float*)d_in[2];  // (2562,3) f32
    float* ws     = (float*)d_ws;
    float* coefEO = ws + OFF_COEF;
    float* Tt     = ws + OFF_TT;
    float* Gt     = ws + OFF_GT;
    float* Gp     = ws + OFF_GP;
    float* Ysp    = ws + OFF_YS;   // aliases Gp (consumed by k_reduceG first)

    k_init   <<<DBLK * NPAIR + F_BINS, 256, 0, stream>>>(taus, coefEO, Tt);
    k_stageA <<<dim3(M_TOTAL / (NBT * WPB), FSPLIT), 128, 0, stream>>>(XXs, coefEO, Gp);
    k_reduceG<<<dim3(K2 / 32, BT_PAD / 64), 256, 0, stream>>>(Gp, Gt);
    k_gemmB  <<<dim3(BT_PAD / 256, D_PAD / 64, KSPB), 256, 0, stream>>>(Gt, Tt, Ysp);
    k_argmax <<<M_TOTAL, 256, 0, stream>>>(Ysp, doas, (float*)d_out);
}